// Round 8
// baseline (7531.065 us; speedup 1.0000x reference)
//
#include <hip/hip_runtime.h>

#define B_SZ 2048
#define FEAT 840
#define HID  256
#define LAT  128
#define NQ   12
#define NEMB 512

#define T_SUB 24
#define HSTR  27    // h1 tile stride (T_SUB+2, +1 pad, odd)
#define H2STR 25    // h2 stride (T_SUB+1, odd); h2 aliased into h1s region

typedef float v2f __attribute__((ext_vector_type(2)));

// numpy pairwise 8-accumulator combine: ((r0+r1)+(r2+r3))+((r4+r5)+(r6+r7))
__device__ __forceinline__ float np8_combine(const float* r) {
    float sA = __fadd_rn(r[0], r[1]);
    float sB = __fadd_rn(r[2], r[3]);
    float sC = __fadd_rn(r[4], r[5]);
    float sD = __fadd_rn(r[6], r[7]);
    return __fadd_rn(__fadd_rn(sA, sB), __fadd_rn(sC, sD));
}

// ---------------- w2 repack, k-major: w2r[c2][ly][k*4+j] ----------------
// per (c2,ly): float4[k] = (w_{j0,k}, w_{j1,k}, w_{j2,k}, w_{j3,k})
__global__ __launch_bounds__(256) void w2r_kernel(const float* __restrict__ w2,
                                                  float* __restrict__ w2r)
{
    int p = blockIdx.x * 256 + threadIdx.x;          // [0, 256*384)
    if (p >= HID * 384) return;
    int c2 = p / 384, r = p - c2 * 384;
    int ly = r / 12, jk = r - ly * 12;
    int k = jk >> 2, j = jk & 3;
    w2r[p] = w2[(size_t)(ly*4 + j)*768 + c2*3 + k];
}

// ---------------- encoder, numpy-f32 bit-faithful ----------------
// one block per batch row; 256 threads = 32 l-groups(4 l) x 8 t-groups(3 t).
template <int USE_WR>
__global__ __launch_bounds__(256) void enc32_kernel(
    const float* __restrict__ x,  const float* __restrict__ w1,
    const float* __restrict__ b1, const float* __restrict__ w2,
    const float* __restrict__ w2r,
    const float* __restrict__ b2, float* __restrict__ zout)
{
    __shared__ float xp[FEAT + 4];        // 3376 B
    __shared__ float h1s[HID * HSTR];     // 27648 B; h2 tile aliased here
    __shared__ float leafs[LAT * 8];      // 4096 B          => 35.1 KB total

    const int tid = threadIdx.x;
    const int b   = blockIdx.x;
    const int tx  = tid & 7;        // t-group (3 t's)
    const int ly  = tid >> 3;       // l-group (4 l's)
    const int u0  = tx * 3;

    const float wA = w1[tid*3+0], wB = w1[tid*3+1], wC = w1[tid*3+2];
    const float b1c = b1[tid];
    float b2v[4];
#pragma unroll
    for (int j = 0; j < 4; ++j) b2v[j] = b2[ly*4 + j];

    for (int i = tid; i < FEAT + 2; i += 256)
        xp[i] = (i >= 1 && i <= FEAT) ? x[(size_t)b*FEAT + i - 1] : 0.f;

    // numpy pairwise-840 leaf state (threads 0..127, one l each)
    float racc[8];
    int leaf_id = 0, leaf_pos = 0;
#pragma unroll
    for (int j = 0; j < 8; ++j) racc[j] = 0.f;

    __syncthreads();
    for (int t0 = 0; t0 < FEAT; t0 += T_SUB) {
        // ---- phase A: h1[c=tid][tp], f32 exact conv1 ----
        const bool edge = (t0 == 0) | (t0 + T_SUB == FEAT);
        if (edge) {
            for (int tp = 0; tp < T_SUB + 2; ++tp) {
                int tg = t0 - 1 + tp;
                float v = 0.f;
                if (tg >= 0 && tg < FEAT) {
                    float s = __fadd_rn(__fadd_rn(__fmul_rn(wA, xp[tg]),
                                                  __fmul_rn(wB, xp[tg+1])),
                                        __fmul_rn(wC, xp[tg+2]));
                    s = __fadd_rn(s, b1c);
                    v = s > 0.f ? s : 0.f;
                }
                h1s[tid*HSTR + tp] = v;
            }
        } else {
#pragma unroll 2
            for (int tp = 0; tp < T_SUB + 2; ++tp) {
                int tg = t0 - 1 + tp;
                float s = __fadd_rn(__fadd_rn(__fmul_rn(wA, xp[tg]),
                                              __fmul_rn(wB, xp[tg+1])),
                                    __fmul_rn(wC, xp[tg+2]));
                s = __fadd_rn(s, b1c);
                h1s[tid*HSTR + tp] = s > 0.f ? s : 0.f;
            }
        }
        __syncthreads();

        if (USE_WR) {
            // ---- phase B: packed-f32 conv2 with next-c2 register prefetch ----
            // acc2[p][i][k]: components = (j=2p, j=2p+1) chains, c2-ascending
            v2f acc2[2][3][3];
#pragma unroll
            for (int p = 0; p < 2; ++p)
#pragma unroll
                for (int i = 0; i < 3; ++i)
#pragma unroll
                    for (int k = 0; k < 3; ++k) acc2[p][i][k] = (v2f){0.f, 0.f};

            const float* __restrict__ wbase = w2r + ly*12;
            const float* __restrict__ hbase = &h1s[u0];

            const float4* wp4 = (const float4*)(wbase);
            float4 wk0 = wp4[0], wk1 = wp4[1], wk2 = wp4[2];
            float hv0 = hbase[0], hv1 = hbase[1], hv2 = hbase[2],
                  hv3 = hbase[3], hv4 = hbase[4];

#define PKSTEP(W0, W1, W2, H0, H1, H2, H3, H4)                                    \
            {                                                                     \
                v2f h00 = {H0, H0}, h11 = {H1, H1}, h22 = {H2, H2};               \
                v2f h33 = {H3, H3}, h44 = {H4, H4};                               \
                acc2[0][0][0] = __builtin_elementwise_fma((v2f){W0.x, W0.y}, h00, acc2[0][0][0]); \
                acc2[1][0][0] = __builtin_elementwise_fma((v2f){W0.z, W0.w}, h00, acc2[1][0][0]); \
                acc2[0][1][0] = __builtin_elementwise_fma((v2f){W0.x, W0.y}, h11, acc2[0][1][0]); \
                acc2[1][1][0] = __builtin_elementwise_fma((v2f){W0.z, W0.w}, h11, acc2[1][1][0]); \
                acc2[0][2][0] = __builtin_elementwise_fma((v2f){W0.x, W0.y}, h22, acc2[0][2][0]); \
                acc2[1][2][0] = __builtin_elementwise_fma((v2f){W0.z, W0.w}, h22, acc2[1][2][0]); \
                acc2[0][0][1] = __builtin_elementwise_fma((v2f){W1.x, W1.y}, h11, acc2[0][0][1]); \
                acc2[1][0][1] = __builtin_elementwise_fma((v2f){W1.z, W1.w}, h11, acc2[1][0][1]); \
                acc2[0][1][1] = __builtin_elementwise_fma((v2f){W1.x, W1.y}, h22, acc2[0][1][1]); \
                acc2[1][1][1] = __builtin_elementwise_fma((v2f){W1.z, W1.w}, h22, acc2[1][1][1]); \
                acc2[0][2][1] = __builtin_elementwise_fma((v2f){W1.x, W1.y}, h33, acc2[0][2][1]); \
                acc2[1][2][1] = __builtin_elementwise_fma((v2f){W1.z, W1.w}, h33, acc2[1][2][1]); \
                acc2[0][0][2] = __builtin_elementwise_fma((v2f){W2.x, W2.y}, h22, acc2[0][0][2]); \
                acc2[1][0][2] = __builtin_elementwise_fma((v2f){W2.z, W2.w}, h22, acc2[1][0][2]); \
                acc2[0][1][2] = __builtin_elementwise_fma((v2f){W2.x, W2.y}, h33, acc2[0][1][2]); \
                acc2[1][1][2] = __builtin_elementwise_fma((v2f){W2.z, W2.w}, h33, acc2[1][1][2]); \
                acc2[0][2][2] = __builtin_elementwise_fma((v2f){W2.x, W2.y}, h44, acc2[0][2][2]); \
                acc2[1][2][2] = __builtin_elementwise_fma((v2f){W2.z, W2.w}, h44, acc2[1][2][2]); \
            }

#pragma unroll 2
            for (int c2 = 0; c2 < HID - 1; ++c2) {
                // prefetch c2+1
                const float4* np4 = (const float4*)(wbase + (size_t)(c2+1)*384);
                float4 nw0 = np4[0], nw1 = np4[1], nw2 = np4[2];
                const float* nhb = hbase + (c2+1)*HSTR;
                float nh0 = nhb[0], nh1 = nhb[1], nh2 = nhb[2],
                      nh3 = nhb[3], nh4 = nhb[4];
                // compute c2
                PKSTEP(wk0, wk1, wk2, hv0, hv1, hv2, hv3, hv4)
                // rotate
                wk0 = nw0; wk1 = nw1; wk2 = nw2;
                hv0 = nh0; hv1 = nh1; hv2 = nh2; hv3 = nh3; hv4 = nh4;
            }
            PKSTEP(wk0, wk1, wk2, hv0, hv1, hv2, hv3, hv4)
#undef PKSTEP
            __syncthreads();   // h1s reads done before h2 overwrites region

            // h2 = fl(fl(m0+m1)+m2) + b2, relu  -> aliased LDS (h1s region)
#pragma unroll
            for (int p = 0; p < 2; ++p)
#pragma unroll
                for (int c = 0; c < 2; ++c) {
                    int j = p*2 + c;
#pragma unroll
                    for (int i = 0; i < 3; ++i) {
                        float m0 = acc2[p][i][0][c];
                        float m1 = acc2[p][i][1][c];
                        float m2 = acc2[p][i][2][c];
                        float hh = __fadd_rn(__fadd_rn(m0, m1), m2);
                        hh = __fadd_rn(hh, b2v[j]);
                        hh = hh > 0.f ? hh : 0.f;
                        h1s[(ly*4 + j)*H2STR + u0 + i] = hh;
                    }
                }
        } else {
            // fallback: scalar chains straight from w2
            float sk[4][3][3];
#pragma unroll
            for (int j = 0; j < 4; ++j)
#pragma unroll
                for (int i = 0; i < 3; ++i)
#pragma unroll
                    for (int k = 0; k < 3; ++k) sk[j][i][k] = 0.f;

            const float* __restrict__ wp = w2 + (size_t)(ly*4)*768;
            for (int c2 = 0; c2 < HID; ++c2) {
                const float* hb = &h1s[c2*HSTR + u0];
                float hv[5];
#pragma unroll
                for (int m = 0; m < 5; ++m) hv[m] = hb[m];
#pragma unroll
                for (int j = 0; j < 4; ++j) {
                    float wa = wp[j*768 + c2*3 + 0];
                    float wb = wp[j*768 + c2*3 + 1];
                    float wc = wp[j*768 + c2*3 + 2];
#pragma unroll
                    for (int i = 0; i < 3; ++i) {
                        sk[j][i][0] = __fmaf_rn(wa, hv[i],   sk[j][i][0]);
                        sk[j][i][1] = __fmaf_rn(wb, hv[i+1], sk[j][i][1]);
                        sk[j][i][2] = __fmaf_rn(wc, hv[i+2], sk[j][i][2]);
                    }
                }
            }
            __syncthreads();
#pragma unroll
            for (int j = 0; j < 4; ++j)
#pragma unroll
                for (int i = 0; i < 3; ++i) {
                    float hh = __fadd_rn(__fadd_rn(sk[j][i][0], sk[j][i][1]), sk[j][i][2]);
                    hh = __fadd_rn(hh, b2v[j]);
                    hh = hh > 0.f ? hh : 0.f;
                    h1s[(ly*4 + j)*H2STR + u0 + i] = hh;
                }
        }
        __syncthreads();

        // reducer: threads 0..127 ingest T_SUB t's in order into numpy leaves
        if (tid < LAT) {
            for (int tt = 0; tt < T_SUB; ++tt) {
                float v = h1s[tid*H2STR + tt];
                int j = leaf_pos & 7;
                racc[j] = (leaf_pos < 8) ? v : __fadd_rn(racc[j], v);
                ++leaf_pos;
                int llen = (leaf_id == 7) ? 112 : 104;
                if (leaf_pos == llen) {
                    leafs[tid*8 + leaf_id] = np8_combine(racc);
                    ++leaf_id; leaf_pos = 0;
                }
            }
        }
        __syncthreads();   // reducer done before next tile's phase A writes h1s
    }

    // numpy pairwise-840 recombination
    if (tid < LAT) {
        const float* L = &leafs[tid*8];
        float s0 = __fadd_rn(L[0], L[1]);
        float s1 = __fadd_rn(L[2], L[3]);
        float sA = __fadd_rn(s0, s1);
        float s2 = __fadd_rn(L[4], L[5]);
        float s3 = __fadd_rn(L[6], L[7]);
        float sB = __fadd_rn(s2, s3);
        float tot = __fadd_rn(sA, sB);
        zout[(size_t)b*LAT + tid] = __fdiv_rn(tot, 840.0f);
    }
}

// ---------------- RVQ, numpy-f32 bit-faithful ----------------
__global__ __launch_bounds__(256) void rvq32_kernel(
    const float* __restrict__ cb, const float* __restrict__ z,
    float* __restrict__ zqout, float* __restrict__ oidx)
{
    __shared__ float rr[LAT];
    __shared__ float Ash;
    __shared__ float redd[256];
    __shared__ int   rede[256];
    __shared__ float sredd[64];
    __shared__ int   srede[64];
    __shared__ int   beste;
    __shared__ float qv[NQ * LAT];

    const int tid = threadIdx.x;
    const int b   = blockIdx.x;

    if (tid < LAT) rr[tid] = z[(size_t)b*LAT + tid];
    __syncthreads();

    for (int q = 0; q < NQ; ++q) {
        const float* __restrict__ cbq = cb + (size_t)q * NEMB * LAT;

        if (tid == 0) {
            float r8[8];
#pragma unroll
            for (int j = 0; j < 8; ++j) r8[j] = __fmul_rn(rr[j], rr[j]);
            for (int i = 8; i < LAT; i += 8)
#pragma unroll
                for (int j = 0; j < 8; ++j)
                    r8[j] = __fadd_rn(r8[j], __fmul_rn(rr[i+j], rr[i+j]));
            Ash = np8_combine(r8);
        }
        __syncthreads();

        float dmin = 0.f; int emin = 0;
#pragma unroll
        for (int h = 0; h < 2; ++h) {
            int e = 2*tid + h;
            const float* __restrict__ cp = cbq + (size_t)e*LAT;
            float dot = 0.f;
            float c8[8];
#pragma unroll
            for (int j = 0; j < 8; ++j) {
                float c = cp[j];
                c8[j] = __fmul_rn(c, c);
                dot = __fmaf_rn(c, rr[j], dot);
            }
            for (int i = 8; i < LAT; i += 8)
#pragma unroll
                for (int j = 0; j < 8; ++j) {
                    float c = cp[i+j];
                    dot = __fmaf_rn(c, rr[i+j], dot);
                    c8[j] = __fadd_rn(c8[j], __fmul_rn(c, c));
                }
            float cn = np8_combine(c8);
            float G  = __fmul_rn(2.0f, dot);
            float d  = __fadd_rn(__fsub_rn(Ash, G), cn);
            if (h == 0) { dmin = d; emin = e; }
            else if (d < dmin) { dmin = d; emin = e; }
        }
        redd[tid] = dmin; rede[tid] = emin;
        __syncthreads();

        if (tid < 64) {
            float bb = redd[tid*4]; int ee = rede[tid*4];
            for (int j = 1; j < 4; ++j) {
                float dj = redd[tid*4 + j];
                if (dj < bb) { bb = dj; ee = rede[tid*4 + j]; }
            }
            sredd[tid] = bb; srede[tid] = ee;
        }
        __syncthreads();
        if (tid == 0) {
            float bb = sredd[0]; int ee = srede[0];
            for (int j = 1; j < 64; ++j) {
                float dj = sredd[j];
                if (dj < bb) { bb = dj; ee = srede[j]; }
            }
            beste = ee;
            oidx[(size_t)b*NQ + q] = (float)ee;
        }
        __syncthreads();

        if (tid < LAT) {
            float cv = cbq[(size_t)beste*LAT + tid];
            qv[q*LAT + tid] = cv;
            rr[tid] = __fsub_rn(rr[tid], cv);
        }
        __syncthreads();
    }

    if (tid < LAT) {
        float s = qv[tid];
        for (int s2 = 1; s2 < NQ; ++s2)
            s = __fadd_rn(s, qv[s2*LAT + tid]);
        zqout[(size_t)b*LAT + tid] = s;
    }
}

extern "C" void kernel_launch(void* const* d_in, const int* in_sizes, int n_in,
                              void* d_out, int out_size, void* d_ws, size_t ws_size,
                              hipStream_t stream)
{
    (void)in_sizes; (void)n_in; (void)out_size;
    const float* x  = (const float*)d_in[0];
    const float* w1 = (const float*)d_in[1];
    const float* b1 = (const float*)d_in[2];
    const float* w2 = (const float*)d_in[3];
    const float* b2 = (const float*)d_in[4];
    const float* cb = (const float*)d_in[5];

    float* out  = (float*)d_out;
    float* zq   = out;                         // 2048*1*128 floats
    float* oidx = out + (size_t)B_SZ * LAT;    // 2048*1*12 floats

    const size_t w2r_bytes = (size_t)HID * 384 * sizeof(float);  // 393216

    if (ws_size >= w2r_bytes) {
        float* w2r = (float*)d_ws;
        w2r_kernel<<<(HID*384 + 255)/256, 256, 0, stream>>>(w2, w2r);
        enc32_kernel<1><<<B_SZ, 256, 0, stream>>>(x, w1, b1, w2, w2r, b2, zq);
    } else {
        enc32_kernel<0><<<B_SZ, 256, 0, stream>>>(x, w1, b1, w2, nullptr, b2, zq);
    }
    rvq32_kernel<<<B_SZ, 256, 0, stream>>>(cb, zq, zq, oidx);
}